// Round 1
// baseline (896.464 us; speedup 1.0000x reference)
//
#include <hip/hip_runtime.h>
#include <cstdint>
#include <math.h>

// Transformer block: LN1 -> QKV -> MHA (attn probs are output[1]) -> proj+res
//                    -> LN2 -> GELU MLP + res -> output[0]
// All GEMMs: fp16 MFMA 16x16x32, 128x128 tiles (BK=32), global_load_lds staging,
// XOR chunk swizzle on LDS (write-side via pre-swizzled global source, rule #21).

typedef _Float16 f16;
typedef _Float16 f16x4 __attribute__((ext_vector_type(4)));
typedef _Float16 f16x8 __attribute__((ext_vector_type(8)));
typedef float f32x4 __attribute__((ext_vector_type(4)));

#define DEV static __device__ __forceinline__

DEV void gload16(const void* g, void* l) {
  __builtin_amdgcn_global_load_lds(
      (__attribute__((address_space(1))) void*)(uintptr_t)g,
      (__attribute__((address_space(3))) void*)(uintptr_t)l, 16, 0, 0);
}

DEV f32x4 mfma16(f16x8 a, f16x8 b, f32x4 c) {
  return __builtin_amdgcn_mfma_f32_16x16x32_f16(a, b, c, 0, 0, 0);
}

// ---- 128x128 NT GEMM core: C_tile = A[128,K] * B[128,K]^T, fp16, fp32 acc ----
// A,B point at the tile's first row. lda/ldb in elements. K % 32 == 0.
// LDS As/Bs: 128 rows x 32 cols, 16B chunks XOR-swizzled: lds_chunk = g_chunk ^ ((row>>1)&3)
DEV void nt_core(const f16* __restrict__ A, const f16* __restrict__ B,
                 int lda, int ldb, int K, f16* As, f16* Bs, f32x4 acc[4][4])
{
  const int tid  = threadIdx.x;
  const int lane = tid & 63;
  const int w    = tid >> 6;
  const int wm   = (w >> 1) << 6;           // 0 / 64
  const int wn   = (w & 1) << 6;
  const int srow = tid >> 2;                // 0..63
  const int scs  = (((tid & 3) ^ ((srow >> 1) & 3)) << 3);  // swizzled src col (elems)
  const size_t aoff0 = (size_t)srow * lda + scs;
  const size_t aoff1 = (size_t)(srow + 64) * lda + scs;     // (+64 doesn't change swizzle)
  const size_t boff0 = (size_t)srow * ldb + scs;
  const size_t boff1 = (size_t)(srow + 64) * ldb + scs;
  f16* la0 = As + tid * 8;
  f16* la1 = As + 2048 + tid * 8;
  f16* lb0 = Bs + tid * 8;
  f16* lb1 = Bs + 2048 + tid * 8;
  const int frow = lane & 15;
  const int fcs  = (((lane >> 4) ^ ((frow >> 1) & 3)) << 3); // swizzled frag col

  for (int k0 = 0; k0 < K; k0 += 32) {
    gload16(A + aoff0 + k0, la0);
    gload16(A + aoff1 + k0, la1);
    gload16(B + boff0 + k0, lb0);
    gload16(B + boff1 + k0, lb1);
    __syncthreads();   // drains vmcnt(0): staged data visible
    f16x8 af[4], bf[4];
#pragma unroll
    for (int i = 0; i < 4; ++i) {
      af[i] = *(const f16x8*)(As + (wm + i * 16 + frow) * 32 + fcs);
      bf[i] = *(const f16x8*)(Bs + (wn + i * 16 + frow) * 32 + fcs);
    }
#pragma unroll
    for (int i = 0; i < 4; ++i)
#pragma unroll
      for (int j = 0; j < 4; ++j)
        acc[i][j] = mfma16(af[i], bf[j], acc[i][j]);
    __syncthreads();   // all reads done before next-tile staging
  }
}

// ---------------- fp32 -> fp16 convert ----------------
__global__ __launch_bounds__(256) void k_cvt(const float* __restrict__ in,
                                             f16* __restrict__ out, int n4)
{
  int i = blockIdx.x * blockDim.x + threadIdx.x;
  if (i >= n4) return;
  float4 f = ((const float4*)in)[i];
  f16x4 o; o[0] = (f16)f.x; o[1] = (f16)f.y; o[2] = (f16)f.z; o[3] = (f16)f.w;
  ((f16x4*)out)[i] = o;
}

// ---------------- LayerNorm (1024 cols, 1 row/block) ----------------
__global__ __launch_bounds__(256) void k_ln(const float* __restrict__ xin,
                                            const float* __restrict__ g,
                                            const float* __restrict__ bb,
                                            f16* __restrict__ out)
{
  __shared__ float red[8];
  const int tid = threadIdx.x;
  const size_t row = blockIdx.x;
  const float4 v = ((const float4*)(xin + row * 1024))[tid];
  float s  = v.x + v.y + v.z + v.w;
  float sq = v.x * v.x + v.y * v.y + v.z * v.z + v.w * v.w;
#pragma unroll
  for (int off = 32; off > 0; off >>= 1) { s += __shfl_xor(s, off); sq += __shfl_xor(sq, off); }
  if ((tid & 63) == 0) { red[tid >> 6] = s; red[4 + (tid >> 6)] = sq; }
  __syncthreads();
  s  = red[0] + red[1] + red[2] + red[3];
  sq = red[4] + red[5] + red[6] + red[7];
  const float mu = s * (1.0f / 1024.0f);
  const float rs = rsqrtf(sq * (1.0f / 1024.0f) - mu * mu + 1e-5f);
  const float4 gg = ((const float4*)g)[tid];
  const float4 bv = ((const float4*)bb)[tid];
  f16x4 o;
  o[0] = (f16)((v.x - mu) * rs * gg.x + bv.x);
  o[1] = (f16)((v.y - mu) * rs * gg.y + bv.y);
  o[2] = (f16)((v.z - mu) * rs * gg.z + bv.z);
  o[3] = (f16)((v.w - mu) * rs * gg.w + bv.w);
  ((f16x4*)(out + row * 1024))[tid] = o;
}

// ---------------- QKV GEMM: [8192,1024] x [3072,1024]^T ----------------
// scatter epilogue into q[bh][n][d], k[bh][n][d], vT[bh][d][n]
__global__ __launch_bounds__(256) void k_qkv(const f16* __restrict__ xn,
                                             const f16* __restrict__ wq,
                                             f16* __restrict__ qb, f16* __restrict__ kb,
                                             f16* __restrict__ vT)
{
  __shared__ __align__(16) f16 As[4096], Bs[4096];
  f32x4 acc[4][4] = {};
  const int bm = blockIdx.x, bn = blockIdx.y;
  nt_core(xn + (size_t)bm * 128 * 1024, wq + (size_t)bn * 128 * 1024,
          1024, 1024, 1024, As, Bs, acc);
  const int tid = threadIdx.x, lane = tid & 63, w = tid >> 6;
  const int r0 = bm * 128 + ((w >> 1) << 6) + ((lane >> 4) << 2);
  const int c0 = bn * 128 + ((w & 1) << 6);
  const int sec = (bn * 128) >> 10;   // 0=q 1=k 2=v (block never crosses a section)
#pragma unroll
  for (int i = 0; i < 4; ++i) {
#pragma unroll
    for (int j = 0; j < 4; ++j) {
      const int o = c0 + j * 16 + (lane & 15);
      const int h = (o & 1023) >> 6, d = o & 63;
#pragma unroll
      for (int e = 0; e < 4; ++e) {
        const int m = r0 + i * 16 + e;
        const int b = m >> 10, n = m & 1023;
        const int bh = (b << 4) + h;
        const f16 val = (f16)acc[i][j][e];
        if (sec == 0)      qb[((size_t)bh * 1024 + n) * 64 + d] = val;
        else if (sec == 1) kb[((size_t)bh * 1024 + n) * 64 + d] = val;
        else               vT[((size_t)bh * 64 + d) * 1024 + n] = val;
      }
    }
  }
}

// ---------------- scores: S = Q K^T * 0.125 -> attn (fp32) ----------------
__global__ __launch_bounds__(256) void k_scores(const f16* __restrict__ qb,
                                                const f16* __restrict__ kb,
                                                float* __restrict__ attn)
{
  __shared__ __align__(16) f16 As[4096], Bs[4096];
  f32x4 acc[4][4] = {};
  const int bh = blockIdx.z;
  nt_core(qb + (size_t)bh * 65536 + (size_t)blockIdx.x * 128 * 64,
          kb + (size_t)bh * 65536 + (size_t)blockIdx.y * 128 * 64,
          64, 64, 64, As, Bs, acc);
  float* out = attn + ((size_t)bh << 20);
  const int tid = threadIdx.x, lane = tid & 63, w = tid >> 6;
  const int r0 = blockIdx.x * 128 + ((w >> 1) << 6) + ((lane >> 4) << 2);
  const int c0 = blockIdx.y * 128 + ((w & 1) << 6) + (lane & 15);
#pragma unroll
  for (int i = 0; i < 4; ++i)
#pragma unroll
    for (int j = 0; j < 4; ++j)
#pragma unroll
      for (int e = 0; e < 4; ++e)
        out[(size_t)(r0 + i * 16 + e) * 1024 + c0 + j * 16] = acc[i][j][e] * 0.125f;
}

// ---------------- row softmax in-place (1024 cols) ----------------
__global__ __launch_bounds__(256) void k_softmax(float* __restrict__ attn)
{
  __shared__ float red[8];
  const int tid = threadIdx.x;
  float* p = attn + (size_t)blockIdx.x * 1024;
  float4 v = ((float4*)p)[tid];
  float m = fmaxf(fmaxf(v.x, v.y), fmaxf(v.z, v.w));
#pragma unroll
  for (int off = 32; off > 0; off >>= 1) m = fmaxf(m, __shfl_xor(m, off));
  if ((tid & 63) == 0) red[tid >> 6] = m;
  __syncthreads();
  m = fmaxf(fmaxf(red[0], red[1]), fmaxf(red[2], red[3]));
  v.x = __expf(v.x - m); v.y = __expf(v.y - m);
  v.z = __expf(v.z - m); v.w = __expf(v.w - m);
  float s = v.x + v.y + v.z + v.w;
#pragma unroll
  for (int off = 32; off > 0; off >>= 1) s += __shfl_xor(s, off);
  if ((tid & 63) == 0) red[4 + (tid >> 6)] = s;
  __syncthreads();
  s = red[4] + red[5] + red[6] + red[7];
  const float inv = 1.0f / s;
  v.x *= inv; v.y *= inv; v.z *= inv; v.w *= inv;
  ((float4*)p)[tid] = v;
}

// ---------------- PV: y = P @ V  (P fp32 -> fp16 reg-staged; V as VT[d][k]) ----
__global__ __launch_bounds__(256) void k_pv(const float* __restrict__ attn,
                                            const f16* __restrict__ vT,
                                            f16* __restrict__ y2)
{
  __shared__ __align__(16) f16 As[128 * 32], Bs[64 * 32];
  f32x4 acc[4][2] = {};
  const int bh = blockIdx.y, m0 = blockIdx.x * 128;
  const float* P = attn + ((size_t)bh << 20) + (size_t)m0 * 1024;
  const f16* V = vT + ((size_t)bh << 16);
  const int tid = threadIdx.x, lane = tid & 63, w = tid >> 6;
  const int wm = (w >> 1) << 6, wn = (w & 1) << 5;
  const int arow = tid >> 1, acb = (tid & 1) << 4;
  const int sw = (arow >> 1) & 3;
  const int ach0 = ((((tid & 1) << 1) ^ sw) << 3);
  const int ach1 = (((((tid & 1) << 1) + 1) ^ sw) << 3);
  const int brow = tid >> 2;
  const int bcs = (((tid & 3) ^ ((brow >> 1) & 3)) << 3);
  const int frow = lane & 15;
  const int fcs = (((lane >> 4) ^ ((frow >> 1) & 3)) << 3);

  for (int k0 = 0; k0 < 1024; k0 += 32) {
    gload16(V + (size_t)brow * 1024 + k0 + bcs, Bs + tid * 8);
    const float4 f0 = *(const float4*)(P + (size_t)arow * 1024 + k0 + acb);
    const float4 f1 = *(const float4*)(P + (size_t)arow * 1024 + k0 + acb + 4);
    const float4 f2 = *(const float4*)(P + (size_t)arow * 1024 + k0 + acb + 8);
    const float4 f3 = *(const float4*)(P + (size_t)arow * 1024 + k0 + acb + 12);
    f16x8 p0, p1;
    p0[0] = (f16)f0.x; p0[1] = (f16)f0.y; p0[2] = (f16)f0.z; p0[3] = (f16)f0.w;
    p0[4] = (f16)f1.x; p0[5] = (f16)f1.y; p0[6] = (f16)f1.z; p0[7] = (f16)f1.w;
    p1[0] = (f16)f2.x; p1[1] = (f16)f2.y; p1[2] = (f16)f2.z; p1[3] = (f16)f2.w;
    p1[4] = (f16)f3.x; p1[5] = (f16)f3.y; p1[6] = (f16)f3.z; p1[7] = (f16)f3.w;
    *(f16x8*)(As + arow * 32 + ach0) = p0;
    *(f16x8*)(As + arow * 32 + ach1) = p1;
    __syncthreads();
    f16x8 af[4], bf[2];
#pragma unroll
    for (int i = 0; i < 4; ++i)
      af[i] = *(const f16x8*)(As + (wm + i * 16 + frow) * 32 + fcs);
#pragma unroll
    for (int j = 0; j < 2; ++j)
      bf[j] = *(const f16x8*)(Bs + (wn + j * 16 + frow) * 32 + fcs);
#pragma unroll
    for (int i = 0; i < 4; ++i)
#pragma unroll
      for (int j = 0; j < 2; ++j)
        acc[i][j] = mfma16(af[i], bf[j], acc[i][j]);
    __syncthreads();
  }
  const int b = bh >> 4, h = bh & 15;
  const int r0 = m0 + wm + ((lane >> 4) << 2);
  const int c0 = (h << 6) + wn + (lane & 15);
#pragma unroll
  for (int i = 0; i < 4; ++i)
#pragma unroll
    for (int j = 0; j < 2; ++j)
#pragma unroll
      for (int e = 0; e < 4; ++e)
        y2[(size_t)(b * 1024 + r0 + i * 16 + e) * 1024 + c0 + j * 16] = (f16)acc[i][j][e];
}

// ---------------- proj: xmid = y2 @ wproj^T + bproj + x ----------------
__global__ __launch_bounds__(256) void k_proj(const f16* __restrict__ y2,
                                              const f16* __restrict__ wp,
                                              const float* __restrict__ bproj,
                                              const float* __restrict__ x,
                                              float* __restrict__ xmid)
{
  __shared__ __align__(16) f16 As[4096], Bs[4096];
  f32x4 acc[4][4] = {};
  nt_core(y2 + (size_t)blockIdx.x * 128 * 1024, wp + (size_t)blockIdx.y * 128 * 1024,
          1024, 1024, 1024, As, Bs, acc);
  const int tid = threadIdx.x, lane = tid & 63, w = tid >> 6;
  const int r0 = blockIdx.x * 128 + ((w >> 1) << 6) + ((lane >> 4) << 2);
  const int c0 = blockIdx.y * 128 + ((w & 1) << 6) + (lane & 15);
#pragma unroll
  for (int i = 0; i < 4; ++i)
#pragma unroll
    for (int j = 0; j < 4; ++j) {
      const int c = c0 + j * 16;
      const float bias = bproj[c];
#pragma unroll
      for (int e = 0; e < 4; ++e) {
        const size_t idx = (size_t)(r0 + i * 16 + e) * 1024 + c;
        xmid[idx] = acc[i][j][e] + bias + x[idx];
      }
    }
}

// ---------------- fc1: h = gelu(xn2 @ wfc1^T + bfc1) ----------------
__global__ __launch_bounds__(256) void k_fc1(const f16* __restrict__ xn,
                                             const f16* __restrict__ wf,
                                             const float* __restrict__ bfc1,
                                             f16* __restrict__ hb)
{
  __shared__ __align__(16) f16 As[4096], Bs[4096];
  f32x4 acc[4][4] = {};
  nt_core(xn + (size_t)blockIdx.x * 128 * 1024, wf + (size_t)blockIdx.y * 128 * 1024,
          1024, 1024, 1024, As, Bs, acc);
  const int tid = threadIdx.x, lane = tid & 63, w = tid >> 6;
  const int r0 = blockIdx.x * 128 + ((w >> 1) << 6) + ((lane >> 4) << 2);
  const int c0 = blockIdx.y * 128 + ((w & 1) << 6) + (lane & 15);
#pragma unroll
  for (int i = 0; i < 4; ++i)
#pragma unroll
    for (int j = 0; j < 4; ++j) {
      const int c = c0 + j * 16;
      const float bias = bfc1[c];
#pragma unroll
      for (int e = 0; e < 4; ++e) {
        const float t = acc[i][j][e] + bias;
        const float ge = 0.5f * t * (1.0f + erff(t * 0.70710678118654752f));
        hb[(size_t)(r0 + i * 16 + e) * 4096 + c] = (f16)ge;
      }
    }
}

// ---------------- fc2: out = h @ wfc2^T + bfc2 + xmid ----------------
__global__ __launch_bounds__(256) void k_fc2(const f16* __restrict__ hb,
                                             const f16* __restrict__ wf,
                                             const float* __restrict__ bfc2,
                                             const float* __restrict__ xmid,
                                             float* __restrict__ out)
{
  __shared__ __align__(16) f16 As[4096], Bs[4096];
  f32x4 acc[4][4] = {};
  nt_core(hb + (size_t)blockIdx.x * 128 * 4096, wf + (size_t)blockIdx.y * 128 * 4096,
          4096, 4096, 4096, As, Bs, acc);
  const int tid = threadIdx.x, lane = tid & 63, w = tid >> 6;
  const int r0 = blockIdx.x * 128 + ((w >> 1) << 6) + ((lane >> 4) << 2);
  const int c0 = blockIdx.y * 128 + ((w & 1) << 6) + (lane & 15);
#pragma unroll
  for (int i = 0; i < 4; ++i)
#pragma unroll
    for (int j = 0; j < 4; ++j) {
      const int c = c0 + j * 16;
      const float bias = bfc2[c];
#pragma unroll
      for (int e = 0; e < 4; ++e) {
        const size_t idx = (size_t)(r0 + i * 16 + e) * 1024 + c;
        out[idx] = acc[i][j][e] + bias + xmid[idx];
      }
    }
}

extern "C" void kernel_launch(void* const* d_in, const int* in_sizes, int n_in,
                              void* d_out, int out_size, void* d_ws, size_t ws_size,
                              hipStream_t stream)
{
  const float* x     = (const float*)d_in[0];
  const float* ln1g  = (const float*)d_in[1];
  const float* ln1b  = (const float*)d_in[2];
  const float* wqkv  = (const float*)d_in[3];
  const float* wproj = (const float*)d_in[4];
  const float* bproj = (const float*)d_in[5];
  const float* ln2g  = (const float*)d_in[6];
  const float* ln2b  = (const float*)d_in[7];
  const float* wfc1  = (const float*)d_in[8];
  const float* bfc1  = (const float*)d_in[9];
  const float* wfc2  = (const float*)d_in[10];
  const float* bfc2  = (const float*)d_in[11];

  char* ws = (char*)d_ws;
  f16* wqkv_h  = (f16*)(ws);                    //  6 MB  [0, 6291456)
  f16* wproj_h = (f16*)(ws + 6291456);          //  2 MB
  f16* wfc1_h  = (f16*)(ws + 8388608);          //  8 MB
  f16* wfc2_h  = (f16*)(ws + 16777216);         //  8 MB
  f16* xn      = (f16*)(ws + 25165824);         // 16 MB (xn1, reused as xn2)
  f16* qb      = (f16*)(ws + 41943040);         // 16 MB
  f16* kb      = (f16*)(ws + 58720256);         // 16 MB
  f16* vT      = (f16*)(ws + 75497472);         // 16 MB
  f16* y2      = (f16*)(ws + 92274688);         // 16 MB
  float* xmid  = (float*)(ws + 109051904);      // 32 MB -> total 142606336 B
  f16* hb      = (f16*)(ws + 41943040);         // 64 MB, aliases qb..y2 (dead by fc1)

  float* out_x = (float*)d_out;
  float* attn  = (float*)d_out + 8388608;

  k_cvt<<<3072, 256, 0, stream>>>(wqkv,  wqkv_h,  786432);
  k_cvt<<<1024, 256, 0, stream>>>(wproj, wproj_h, 262144);
  k_cvt<<<4096, 256, 0, stream>>>(wfc1,  wfc1_h,  1048576);
  k_cvt<<<4096, 256, 0, stream>>>(wfc2,  wfc2_h,  1048576);

  k_ln<<<8192, 256, 0, stream>>>(x, ln1g, ln1b, xn);
  k_qkv<<<dim3(64, 24), 256, 0, stream>>>(xn, wqkv_h, qb, kb, vT);
  k_scores<<<dim3(8, 8, 128), 256, 0, stream>>>(qb, kb, attn);
  k_softmax<<<131072, 256, 0, stream>>>(attn);
  k_pv<<<dim3(8, 128), 256, 0, stream>>>(attn, vT, y2);
  k_proj<<<dim3(64, 8), 256, 0, stream>>>(y2, wproj_h, bproj, x, xmid);
  k_ln<<<8192, 256, 0, stream>>>(xmid, ln2g, ln2b, xn);
  k_fc1<<<dim3(64, 32), 256, 0, stream>>>(xn, wfc1_h, bfc1, hb);
  k_fc2<<<dim3(64, 8), 256, 0, stream>>>(hb, wfc2_h, bfc2, xmid, out_x);
}

// Round 2
// 640.094 us; speedup vs baseline: 1.4005x; 1.4005x over previous
//
#include <hip/hip_runtime.h>
#include <cstdint>
#include <math.h>

// Transformer block: LN1 -> QKV -> fused MHA (scores+softmax+PV, attn probs are
// output[1]) -> proj+res -> LN2 -> GELU MLP + res -> output[0]
// GEMMs: fp16 MFMA 16x16x32. Big GEMMs: 128x128 tiles (BK=32), global_load_lds
// staging, XOR chunk swizzle (write-side via pre-swizzled global source).

typedef _Float16 f16;
typedef _Float16 f16x4 __attribute__((ext_vector_type(4)));
typedef _Float16 f16x8 __attribute__((ext_vector_type(8)));
typedef float f32x4 __attribute__((ext_vector_type(4)));

#define DEV static __device__ __forceinline__

DEV void gload16(const void* g, void* l) {
  __builtin_amdgcn_global_load_lds(
      (__attribute__((address_space(1))) void*)(uintptr_t)g,
      (__attribute__((address_space(3))) void*)(uintptr_t)l, 16, 0, 0);
}

DEV f32x4 mfma16(f16x8 a, f16x8 b, f32x4 c) {
  return __builtin_amdgcn_mfma_f32_16x16x32_f16(a, b, c, 0, 0, 0);
}

// ---- 128x128 NT GEMM core: C_tile = A[128,K] * B[128,K]^T, fp16, fp32 acc ----
DEV void nt_core(const f16* __restrict__ A, const f16* __restrict__ B,
                 int lda, int ldb, int K, f16* As, f16* Bs, f32x4 acc[4][4])
{
  const int tid  = threadIdx.x;
  const int lane = tid & 63;
  const int w    = tid >> 6;
  const int wm   = (w >> 1) << 6;
  const int wn   = (w & 1) << 6;
  const int srow = tid >> 2;
  const int scs  = (((tid & 3) ^ ((srow >> 1) & 3)) << 3);
  const size_t aoff0 = (size_t)srow * lda + scs;
  const size_t aoff1 = (size_t)(srow + 64) * lda + scs;
  const size_t boff0 = (size_t)srow * ldb + scs;
  const size_t boff1 = (size_t)(srow + 64) * ldb + scs;
  f16* la0 = As + tid * 8;
  f16* la1 = As + 2048 + tid * 8;
  f16* lb0 = Bs + tid * 8;
  f16* lb1 = Bs + 2048 + tid * 8;
  const int frow = lane & 15;
  const int fcs  = (((lane >> 4) ^ ((frow >> 1) & 3)) << 3);

  for (int k0 = 0; k0 < K; k0 += 32) {
    gload16(A + aoff0 + k0, la0);
    gload16(A + aoff1 + k0, la1);
    gload16(B + boff0 + k0, lb0);
    gload16(B + boff1 + k0, lb1);
    __syncthreads();
    f16x8 af[4], bf[4];
#pragma unroll
    for (int i = 0; i < 4; ++i) {
      af[i] = *(const f16x8*)(As + (wm + i * 16 + frow) * 32 + fcs);
      bf[i] = *(const f16x8*)(Bs + (wn + i * 16 + frow) * 32 + fcs);
    }
#pragma unroll
    for (int i = 0; i < 4; ++i)
#pragma unroll
      for (int j = 0; j < 4; ++j)
        acc[i][j] = mfma16(af[i], bf[j], acc[i][j]);
    __syncthreads();
  }
}

// ---------------- fp32 -> fp16 convert ----------------
__global__ __launch_bounds__(256) void k_cvt(const float* __restrict__ in,
                                             f16* __restrict__ out, int n4)
{
  int i = blockIdx.x * blockDim.x + threadIdx.x;
  if (i >= n4) return;
  float4 f = ((const float4*)in)[i];
  f16x4 o; o[0] = (f16)f.x; o[1] = (f16)f.y; o[2] = (f16)f.z; o[3] = (f16)f.w;
  ((f16x4*)out)[i] = o;
}

// ---------------- LayerNorm (1024 cols, 1 row/block) ----------------
__global__ __launch_bounds__(256) void k_ln(const float* __restrict__ xin,
                                            const float* __restrict__ g,
                                            const float* __restrict__ bb,
                                            f16* __restrict__ out)
{
  __shared__ float red[8];
  const int tid = threadIdx.x;
  const size_t row = blockIdx.x;
  const float4 v = ((const float4*)(xin + row * 1024))[tid];
  float s  = v.x + v.y + v.z + v.w;
  float sq = v.x * v.x + v.y * v.y + v.z * v.z + v.w * v.w;
#pragma unroll
  for (int off = 32; off > 0; off >>= 1) { s += __shfl_xor(s, off); sq += __shfl_xor(sq, off); }
  if ((tid & 63) == 0) { red[tid >> 6] = s; red[4 + (tid >> 6)] = sq; }
  __syncthreads();
  s  = red[0] + red[1] + red[2] + red[3];
  sq = red[4] + red[5] + red[6] + red[7];
  const float mu = s * (1.0f / 1024.0f);
  const float rs = rsqrtf(sq * (1.0f / 1024.0f) - mu * mu + 1e-5f);
  const float4 gg = ((const float4*)g)[tid];
  const float4 bv = ((const float4*)bb)[tid];
  f16x4 o;
  o[0] = (f16)((v.x - mu) * rs * gg.x + bv.x);
  o[1] = (f16)((v.y - mu) * rs * gg.y + bv.y);
  o[2] = (f16)((v.z - mu) * rs * gg.z + bv.z);
  o[3] = (f16)((v.w - mu) * rs * gg.w + bv.w);
  ((f16x4*)(out + row * 1024))[tid] = o;
}

// ---------------- QKV GEMM: [8192,1024] x [3072,1024]^T ----------------
__global__ __launch_bounds__(256) void k_qkv(const f16* __restrict__ xn,
                                             const f16* __restrict__ wq,
                                             f16* __restrict__ qb, f16* __restrict__ kb,
                                             f16* __restrict__ vT)
{
  __shared__ __align__(16) f16 As[4096], Bs[4096];
  f32x4 acc[4][4] = {};
  const int bm = blockIdx.x, bn = blockIdx.y;
  nt_core(xn + (size_t)bm * 128 * 1024, wq + (size_t)bn * 128 * 1024,
          1024, 1024, 1024, As, Bs, acc);
  const int tid = threadIdx.x, lane = tid & 63, w = tid >> 6;
  const int r0 = bm * 128 + ((w >> 1) << 6) + ((lane >> 4) << 2);
  const int c0 = bn * 128 + ((w & 1) << 6);
  const int sec = (bn * 128) >> 10;
#pragma unroll
  for (int i = 0; i < 4; ++i) {
#pragma unroll
    for (int j = 0; j < 4; ++j) {
      const int o = c0 + j * 16 + (lane & 15);
      const int h = (o & 1023) >> 6, d = o & 63;
#pragma unroll
      for (int e = 0; e < 4; ++e) {
        const int m = r0 + i * 16 + e;
        const int b = m >> 10, n = m & 1023;
        const int bh = (b << 4) + h;
        const f16 val = (f16)acc[i][j][e];
        if (sec == 0)      qb[((size_t)bh * 1024 + n) * 64 + d] = val;
        else if (sec == 1) kb[((size_t)bh * 1024 + n) * 64 + d] = val;
        else               vT[((size_t)bh * 64 + d) * 1024 + n] = val;
      }
    }
  }
}

// ---------------- fused attention: S=QK^T*scale, softmax, attn out, y=PV ------
// block = (row-tile of 32 q rows) x (bh).  LDS: P[32][1024] fp16, chunk-swizzled:
// elem (r,c) at r*1024 + (((c>>3) ^ (r&7))<<3) + (c&7)
__global__ __launch_bounds__(256) void k_attn(const f16* __restrict__ qb,
                                              const f16* __restrict__ kb,
                                              const f16* __restrict__ vT,
                                              float* __restrict__ attn,
                                              f16* __restrict__ y2)
{
  __shared__ __align__(16) f16 P[32 * 1024];   // exactly 64 KB
  const int tid = threadIdx.x, lane = tid & 63, w = tid >> 6;
  const int lr = lane & 15, lg = lane >> 4;
  const int bh = blockIdx.y;
  const int m0 = blockIdx.x * 32;
  const f16* Qb = qb + ((size_t)bh << 16);
  const f16* Kb = kb + ((size_t)bh << 16);
  const f16* Vt = vT + ((size_t)bh << 16);

  // Q fragments (persistent): rows m0 + i*16 + lr, k-chunk ks*32 + lg*8
  f16x8 qf[2][2];
#pragma unroll
  for (int i = 0; i < 2; ++i)
#pragma unroll
    for (int ks = 0; ks < 2; ++ks)
      qf[i][ks] = *(const f16x8*)(Qb + (size_t)(m0 + i * 16 + lr) * 64 + ks * 32 + lg * 8);

  // ---- phase 1: S = Q K^T * 0.125 -> P_lds (fp16). wave w owns cols [w*256, w*256+256)
  for (int cc = 0; cc < 4; ++cc) {
    const int cb = (w << 8) + (cc << 6);
    f16x8 bf[4][2];
#pragma unroll
    for (int j = 0; j < 4; ++j)
#pragma unroll
      for (int ks = 0; ks < 2; ++ks)
        bf[j][ks] = *(const f16x8*)(Kb + (size_t)(cb + j * 16 + lr) * 64 + ks * 32 + lg * 8);
    f32x4 acc[2][4] = {};
#pragma unroll
    for (int i = 0; i < 2; ++i)
#pragma unroll
      for (int j = 0; j < 4; ++j) {
        acc[i][j] = mfma16(qf[i][0], bf[j][0], acc[i][j]);
        acc[i][j] = mfma16(qf[i][1], bf[j][1], acc[i][j]);
      }
#pragma unroll
    for (int i = 0; i < 2; ++i)
#pragma unroll
      for (int j = 0; j < 4; ++j)
#pragma unroll
        for (int e = 0; e < 4; ++e) {
          const int r = i * 16 + (lg << 2) + e;
          const int c = cb + j * 16 + lr;
          P[(r << 10) + (((c >> 3) ^ (r & 7)) << 3) + (c & 7)] = (f16)(acc[i][j][e] * 0.125f);
        }
  }
  __syncthreads();

  // ---- phase 2: per-row softmax. thread t owns row t>>3, chunk slots (t&7)+8q
  const int r2 = tid >> 3;
  f16* Prow = P + (r2 << 10);
  const int rx = r2 & 7;
  float mrow = -1e30f;
#pragma unroll
  for (int q = 0; q < 16; ++q) {
    const int c = (tid & 7) + (q << 3);
    f16x8 v = *(const f16x8*)(Prow + ((c ^ rx) << 3));
#pragma unroll
    for (int e = 0; e < 8; ++e) mrow = fmaxf(mrow, (float)v[e]);
  }
  mrow = fmaxf(mrow, __shfl_xor(mrow, 1));
  mrow = fmaxf(mrow, __shfl_xor(mrow, 2));
  mrow = fmaxf(mrow, __shfl_xor(mrow, 4));
  float ssum = 0.f;
#pragma unroll
  for (int q = 0; q < 16; ++q) {
    const int c = (tid & 7) + (q << 3);
    f16x8 v = *(const f16x8*)(Prow + ((c ^ rx) << 3));
    f16x8 o;
#pragma unroll
    for (int e = 0; e < 8; ++e) {
      const float ev = __expf((float)v[e] - mrow);
      ssum += ev;
      o[e] = (f16)ev;
    }
    *(f16x8*)(Prow + ((c ^ rx) << 3)) = o;
  }
  ssum += __shfl_xor(ssum, 1);
  ssum += __shfl_xor(ssum, 2);
  ssum += __shfl_xor(ssum, 4);
  const float inv = 1.0f / ssum;
  // normalize: write fp32 attn (coalesced) + normalized fp16 back to LDS
  float* Aout = attn + ((size_t)bh << 20) + ((size_t)(m0 + r2) << 10);
#pragma unroll
  for (int q = 0; q < 16; ++q) {
    const int c = (tid & 7) + (q << 3);
    f16x8 v = *(const f16x8*)(Prow + ((c ^ rx) << 3));
    f16x8 nv;
    float4 o0, o1;
    o0.x = (float)v[0] * inv; o0.y = (float)v[1] * inv;
    o0.z = (float)v[2] * inv; o0.w = (float)v[3] * inv;
    o1.x = (float)v[4] * inv; o1.y = (float)v[5] * inv;
    o1.z = (float)v[6] * inv; o1.w = (float)v[7] * inv;
#pragma unroll
    for (int e = 0; e < 8; ++e) nv[e] = (f16)((float)v[e] * inv);
    ((float4*)(Aout + (c << 3)))[0] = o0;
    ((float4*)(Aout + (c << 3)))[1] = o1;
    *(f16x8*)(Prow + ((c ^ rx) << 3)) = nv;
  }
  __syncthreads();

  // ---- phase 3: y = P @ V. wave w owns d-cols [w*16, w*16+16). V direct from global.
  const int dc = w << 4;
  f32x4 acc2[2] = {};
#pragma unroll 4
  for (int k0 = 0; k0 < 1024; k0 += 32) {
    const f16x8 bf = *(const f16x8*)(Vt + (size_t)(dc + lr) * 1024 + k0 + lg * 8);
#pragma unroll
    for (int i = 0; i < 2; ++i) {
      const int ra = i * 16 + lr;
      const int ch = (k0 >> 3) + lg;
      const f16x8 af = *(const f16x8*)(P + (ra << 10) + ((ch ^ (ra & 7)) << 3));
      acc2[i] = mfma16(af, bf, acc2[i]);
    }
  }
  const int b = bh >> 4, h = bh & 15;
#pragma unroll
  for (int i = 0; i < 2; ++i)
#pragma unroll
    for (int e = 0; e < 4; ++e) {
      const int rloc = i * 16 + (lg << 2) + e;
      y2[(size_t)(b * 1024 + m0 + rloc) * 1024 + (h << 6) + dc + lr] = (f16)acc2[i][e];
    }
}

// ---------------- proj: xmid = y2 @ wproj^T + bproj + x ----------------
__global__ __launch_bounds__(256) void k_proj(const f16* __restrict__ y2,
                                              const f16* __restrict__ wp,
                                              const float* __restrict__ bproj,
                                              const float* __restrict__ x,
                                              float* __restrict__ xmid)
{
  __shared__ __align__(16) f16 As[4096], Bs[4096];
  f32x4 acc[4][4] = {};
  nt_core(y2 + (size_t)blockIdx.x * 128 * 1024, wp + (size_t)blockIdx.y * 128 * 1024,
          1024, 1024, 1024, As, Bs, acc);
  const int tid = threadIdx.x, lane = tid & 63, w = tid >> 6;
  const int r0 = blockIdx.x * 128 + ((w >> 1) << 6) + ((lane >> 4) << 2);
  const int c0 = blockIdx.y * 128 + ((w & 1) << 6) + (lane & 15);
#pragma unroll
  for (int i = 0; i < 4; ++i)
#pragma unroll
    for (int j = 0; j < 4; ++j) {
      const int c = c0 + j * 16;
      const float bias = bproj[c];
#pragma unroll
      for (int e = 0; e < 4; ++e) {
        const size_t idx = (size_t)(r0 + i * 16 + e) * 1024 + c;
        xmid[idx] = acc[i][j][e] + bias + x[idx];
      }
    }
}

// ---------------- fc1: h = gelu(xn2 @ wfc1^T + bfc1) ----------------
__global__ __launch_bounds__(256) void k_fc1(const f16* __restrict__ xn,
                                             const f16* __restrict__ wf,
                                             const float* __restrict__ bfc1,
                                             f16* __restrict__ hb)
{
  __shared__ __align__(16) f16 As[4096], Bs[4096];
  f32x4 acc[4][4] = {};
  nt_core(xn + (size_t)blockIdx.x * 128 * 1024, wf + (size_t)blockIdx.y * 128 * 1024,
          1024, 1024, 1024, As, Bs, acc);
  const int tid = threadIdx.x, lane = tid & 63, w = tid >> 6;
  const int r0 = blockIdx.x * 128 + ((w >> 1) << 6) + ((lane >> 4) << 2);
  const int c0 = blockIdx.y * 128 + ((w & 1) << 6) + (lane & 15);
#pragma unroll
  for (int i = 0; i < 4; ++i)
#pragma unroll
    for (int j = 0; j < 4; ++j) {
      const int c = c0 + j * 16;
      const float bias = bfc1[c];
#pragma unroll
      for (int e = 0; e < 4; ++e) {
        const float t = acc[i][j][e] + bias;
        const float ge = 0.5f * t * (1.0f + erff(t * 0.70710678118654752f));
        hb[(size_t)(r0 + i * 16 + e) * 4096 + c] = (f16)ge;
      }
    }
}

// ---------------- fc2: out = h @ wfc2^T + bfc2 + xmid ----------------
__global__ __launch_bounds__(256) void k_fc2(const f16* __restrict__ hb,
                                             const f16* __restrict__ wf,
                                             const float* __restrict__ bfc2,
                                             const float* __restrict__ xmid,
                                             float* __restrict__ out)
{
  __shared__ __align__(16) f16 As[4096], Bs[4096];
  f32x4 acc[4][4] = {};
  nt_core(hb + (size_t)blockIdx.x * 128 * 4096, wf + (size_t)blockIdx.y * 128 * 4096,
          4096, 4096, 4096, As, Bs, acc);
  const int tid = threadIdx.x, lane = tid & 63, w = tid >> 6;
  const int r0 = blockIdx.x * 128 + ((w >> 1) << 6) + ((lane >> 4) << 2);
  const int c0 = blockIdx.y * 128 + ((w & 1) << 6) + (lane & 15);
#pragma unroll
  for (int i = 0; i < 4; ++i)
#pragma unroll
    for (int j = 0; j < 4; ++j) {
      const int c = c0 + j * 16;
      const float bias = bfc2[c];
#pragma unroll
      for (int e = 0; e < 4; ++e) {
        const size_t idx = (size_t)(r0 + i * 16 + e) * 1024 + c;
        out[idx] = acc[i][j][e] + bias + xmid[idx];
      }
    }
}

extern "C" void kernel_launch(void* const* d_in, const int* in_sizes, int n_in,
                              void* d_out, int out_size, void* d_ws, size_t ws_size,
                              hipStream_t stream)
{
  const float* x     = (const float*)d_in[0];
  const float* ln1g  = (const float*)d_in[1];
  const float* ln1b  = (const float*)d_in[2];
  const float* wqkv  = (const float*)d_in[3];
  const float* wproj = (const float*)d_in[4];
  const float* bproj = (const float*)d_in[5];
  const float* ln2g  = (const float*)d_in[6];
  const float* ln2b  = (const float*)d_in[7];
  const float* wfc1  = (const float*)d_in[8];
  const float* bfc1  = (const float*)d_in[9];
  const float* wfc2  = (const float*)d_in[10];
  const float* bfc2  = (const float*)d_in[11];

  char* ws = (char*)d_ws;
  f16* wqkv_h  = (f16*)(ws);                    //  6 MB
  f16* wproj_h = (f16*)(ws + 6291456);          //  2 MB
  f16* wfc1_h  = (f16*)(ws + 8388608);          //  8 MB
  f16* wfc2_h  = (f16*)(ws + 16777216);         //  8 MB
  f16* xn      = (f16*)(ws + 25165824);         // 16 MB (xn1, reused as xn2)
  f16* qb      = (f16*)(ws + 41943040);         // 16 MB
  f16* kb      = (f16*)(ws + 58720256);         // 16 MB
  f16* vT      = (f16*)(ws + 75497472);         // 16 MB
  f16* y2      = (f16*)(ws + 92274688);         // 16 MB
  float* xmid  = (float*)(ws + 109051904);      // 32 MB
  f16* hb      = (f16*)(ws + 41943040);         // 64 MB, aliases qb..y2 (dead by fc1)

  float* out_x = (float*)d_out;
  float* attn  = (float*)d_out + 8388608;

  k_cvt<<<3072, 256, 0, stream>>>(wqkv,  wqkv_h,  786432);
  k_cvt<<<1024, 256, 0, stream>>>(wproj, wproj_h, 262144);
  k_cvt<<<4096, 256, 0, stream>>>(wfc1,  wfc1_h,  1048576);
  k_cvt<<<4096, 256, 0, stream>>>(wfc2,  wfc2_h,  1048576);

  k_ln<<<8192, 256, 0, stream>>>(x, ln1g, ln1b, xn);
  k_qkv<<<dim3(64, 24), 256, 0, stream>>>(xn, wqkv_h, qb, kb, vT);
  k_attn<<<dim3(32, 128), 256, 0, stream>>>(qb, kb, vT, attn, y2);
  k_proj<<<dim3(64, 8), 256, 0, stream>>>(y2, wproj_h, bproj, x, xmid);
  k_ln<<<8192, 256, 0, stream>>>(xmid, ln2g, ln2b, xn);
  k_fc1<<<dim3(64, 32), 256, 0, stream>>>(xn, wfc1_h, bfc1, hb);
  k_fc2<<<dim3(64, 8), 256, 0, stream>>>(hb, wfc2_h, bfc2, xmid, out_x);
}